// Round 9
// baseline (164.365 us; speedup 1.0000x reference)
//
#include <hip/hip_runtime.h>
#include <hip/hip_bf16.h>
#include <math.h>

#define Bq 4
#define Cq 64
#define Hq 160
#define Wq 160
#define HWq (Hq*Wq)      // 25600
#define OUTq 64
#define KKq 576          // Cq*9
#define KS  18           // KKq/32
#define HSTRIDE 72       // halo px stride (ushorts) = 144 B

typedef __attribute__((ext_vector_type(8))) short short8;
typedef __attribute__((ext_vector_type(4))) float float4v;
typedef __attribute__((ext_vector_type(2))) float float2v;
typedef unsigned short ushort_t;
typedef unsigned int uint_t;

__device__ __forceinline__ unsigned int f2bfu(float f) {   // RNE, as uint
    unsigned int u = __builtin_bit_cast(unsigned int, f);
    unsigned int r = u + 0x7fffu + ((u >> 16) & 1u);
    return r >> 16;
}
__device__ __forceinline__ float bflo(unsigned int u) {
    return __builtin_bit_cast(float, u << 16);
}
__device__ __forceinline__ float bfhi(unsigned int u) {
    return __builtin_bit_cast(float, u & 0xffff0000u);
}
__device__ __forceinline__ uint_t packbf(float a, float b) {   // lo=a, hi=b
    return f2bfu(a) | (f2bfu(b) << 16);
}
__device__ __forceinline__ uint_t pkbf2(float2v v) {
    return f2bfu(v.x) | (f2bfu(v.y) << 16);
}
#define MFMA(a,b,c) __builtin_amdgcn_mfma_f32_16x16x32_bf16((a),(b),(c),0,0,0)

// ---------------------------------------------------------------------------
// K_prep: x NCHW f32 -> xt NHWC bf16; weight prepack on first 216 blocks.
//  wtf: A-frags of dcn_w, k-major kk = k*64+c, 4 m-tiles.
//  cwf2: per-tap conv A-frags (27 rows offset+mask, zero-padded to 32).
// ---------------------------------------------------------------------------
__global__ void __launch_bounds__(256) k_prep(const float* __restrict__ x,
                                              const float* __restrict__ dcn_w,
                                              const float* __restrict__ off_w,
                                              const float* __restrict__ msk_w,
                                              ushort_t* __restrict__ xt,
                                              ushort_t* __restrict__ wtf,
                                              ushort_t* __restrict__ cwf2) {
    __shared__ float tile[64][65];
    int b = blockIdx.y, hw0 = blockIdx.x * 64;
    int tid = threadIdx.x;
    int lane = tid & 63, grp = tid >> 6;
#pragma unroll
    for (int i = 0; i < 16; ++i) {
        int c = grp*16 + i;
        tile[c][lane] = x[(b*Cq + c)*HWq + hw0 + lane];
    }
    __syncthreads();
    int cp = tid & 31, hwg = tid >> 5;
#pragma unroll
    for (int it = 0; it < 8; ++it) {
        int hw = it*8 + hwg;
        unsigned int v = f2bfu(tile[2*cp][hw]) | (f2bfu(tile[2*cp+1][hw]) << 16);
        *(unsigned int*)(xt + ((size_t)b*HWq + hw0 + hw)*64 + 2*cp) = v;
    }
    if (blockIdx.y == 0 && blockIdx.x < 216) {
        int id = blockIdx.x*256 + tid;
        if (id < 4*KS*512) {
            int j = id & 7, ln = (id>>3) & 63, ks = (id>>9) % KS, g = id/(512*KS);
            int kk = ks*32 + (ln>>4)*8 + j;
            int c  = kk & 63, kt = kk >> 6;
            int m  = g*16 + (ln&15);
            wtf[id] = (ushort_t)f2bfu(dcn_w[m*KKq + c*9 + kt]);
        }
        int id2 = id - 4*KS*512;
        if (id2 >= 0 && id2 < 9*2*2*512) {
            int j = id2 & 7, ln = (id2>>3) & 63;
            int ks2 = (id2>>9) & 1, g = (id2>>10) & 1, k = id2 >> 11;
            int co = g*16 + (ln&15);
            int c  = ks2*32 + (ln>>4)*8 + j;
            float w = 0.f;
            if (co < 18)      w = off_w[co*KKq + c*9 + k];
            else if (co < 27) w = msk_w[(co-18)*KKq + c*9 + k];
            cwf2[id2] = (ushort_t)f2bfu(w);
        }
    }
}

// ---------------------------------------------------------------------------
// K_fused: block = 4 rows x 16 px. Wave w owns row i0+w and ALL 64 outputs.
//  1) halo stage 6x18x64ch -> LDS
//  2) conv: per-wave full-K MFMA (27x16 per row), partials -> s_part
//  3) Phase A: descriptors (ushort corner idx + bf16 premasked weights),
//     overlaying the halo region
//  4) merged sample+GEMM: per ks, each lane gathers 4 corner dwordx4 from
//     global NHWC xt and combines DIRECTLY into the MFMA B-fragment
//     (no LDS staging, no barriers, no bank conflicts), 4 m-tile MFMAs.
// LDS: max(halo 15552, desc 9216) + s_part 8192 = 23744 B -> 6 blocks/CU.
// ---------------------------------------------------------------------------
__global__ void __launch_bounds__(256, 6) k_fused(const ushort_t* __restrict__ xt,
                                                  const ushort_t* __restrict__ cwf2,
                                                  const float* __restrict__ off_b,
                                                  const float* __restrict__ msk_b,
                                                  const ushort_t* __restrict__ wtf,
                                                  float* __restrict__ out) {
    __shared__ __align__(16) char s_halo[6*18*HSTRIDE*2];    // 15,552 B
    __shared__ __align__(16) float s_part[4*2*64*4];         //  8,192 B

    // XCD swizzle: 8 chunks of 200 blocks = 80 contiguous rows each (~1.6MB)
    int m = blockIdx.x;                   // grid 1600
    int blk = (m & 7)*200 + (m >> 3);
    int jt = blk % 10, it = (blk/10) % 40, b = blk/400;
    int i0 = it*4, j0 = jt*16;
    int tid = threadIdx.x, lane = tid & 63, w = tid >> 6;
    int n = lane & 15, quad = lane >> 4;

    const ushort_t* xtb = xt + (size_t)b*HWq*64;
    ushort_t* halo = (ushort_t*)s_halo;

    // ---- 1) halo: rows i0-1 .. i0+4, px j0-1 .. j0+16 ----
    for (int t = tid; t < 864; t += 256) {
        int seg = t >> 3, sub = t & 7;
        int ry = seg / 18, px = seg % 18;
        int y = i0 + ry - 1, xx = j0 + px - 1;
        uint4 v = {0u,0u,0u,0u};
        if (y >= 0 && y < Hq && xx >= 0 && xx < Wq)
            v = *(const uint4*)(xtb + ((size_t)y*Wq + xx)*64 + sub*8);
        *(uint4*)(halo + (ry*18 + px)*HSTRIDE + sub*8) = v;
    }
    __syncthreads();

    // ---- 2) conv for own row (full K per wave, 2 m-tiles) ----
    {
        float4v c0 = {0.f,0.f,0.f,0.f}, c1 = {0.f,0.f,0.f,0.f};
#pragma unroll
        for (int k = 0; k < 9; ++k) {
            int ky = k/3, kx = k - (k/3)*3;
            const ushort_t* bb = halo + ((w + ky)*18 + n + kx)*HSTRIDE + quad*8;
#pragma unroll
            for (int ks2 = 0; ks2 < 2; ++ks2) {
                short8 bf = *(const short8*)(bb + ks2*32);
                short8 a0 = *(const short8*)(cwf2 + (size_t)(((k*2+0)*2+ks2)*512 + lane*8));
                short8 a1 = *(const short8*)(cwf2 + (size_t)(((k*2+1)*2+ks2)*512 + lane*8));
                c0 = MFMA(a0, bf, c0);
                c1 = MFMA(a1, bf, c1);
            }
        }
        *(float4v*)(s_part + ((w*2+0)*64 + lane)*4) = c0;
        *(float4v*)(s_part + ((w*2+1)*64 + lane)*4) = c1;
    }
    __syncthreads();

    // ---- 3) Phase A: descriptors (overlay halo) ----
    uint4* desc = (uint4*)s_halo;         // 576 x 16 B
    for (int t = tid; t < 576; t += 256) {
        int p = t & 63, k = t >> 6;
        int pw = p >> 4, pn = p & 15;
        #define RD(co) s_part[((pw*2 + ((co)>>4))*64 + (((co)&15)>>2)*16 + pn)*4 + ((co)&3)]
        float oy = RD(2*k)   + off_b[2*k];
        float ox = RD(2*k+1) + off_b[2*k+1];
        float mv = RD(18+k)  + msk_b[k];
        #undef RD
        float mk = 1.f/(1.f + __expf(-mv));
        float py = oy + (float)(i0 + pw - 1 + k/3);
        float px = ox + (float)(j0 + pn - 1 + (k - (k/3)*3));
        float fy = floorf(py), fx = floorf(px);
        int y0 = (int)fy, x0 = (int)fx;
        float wy1 = py - fy, wx1 = px - fx;
        float wy0 = 1.f - wy1, wx0 = 1.f - wx1;
        bool vy0 = (y0 >= 0) & (y0 < Hq),   vy1 = (y0+1 >= 0) & (y0+1 < Hq);
        bool vx0 = (x0 >= 0) & (x0 < Wq),   vx1 = (x0+1 >= 0) & (x0+1 < Wq);
        int yc0 = min(max(y0,   0), Hq-1), yc1 = min(max(y0+1, 0), Hq-1);
        int xc0 = min(max(x0,   0), Wq-1), xc1 = min(max(x0+1, 0), Wq-1);
        uint_t i00 = (uint_t)(yc0*Wq + xc0), i01 = (uint_t)(yc0*Wq + xc1);
        uint_t i10 = (uint_t)(yc1*Wq + xc0), i11 = (uint_t)(yc1*Wq + xc1);
        float w00 = (vy0 && vx0) ? wy0*wx0*mk : 0.f;
        float w01 = (vy0 && vx1) ? wy0*wx1*mk : 0.f;
        float w10 = (vy1 && vx0) ? wy1*wx0*mk : 0.f;
        float w11 = (vy1 && vx1) ? wy1*wx1*mk : 0.f;
        desc[p*9 + k] = make_uint4(i00 | (i01 << 16), i10 | (i11 << 16),
                                   packbf(w00, w01), packbf(w10, w11));
    }
    __syncthreads();

    // ---- 4) merged sampling + GEMM (barrier-free, in-register B-frags) ----
    int i = i0 + w;
    const char* xtc = (const char*)xtb;
    const char* wtc = (const char*)wtf;
    float4v acc[4] = {{0.f,0.f,0.f,0.f},{0.f,0.f,0.f,0.f},
                      {0.f,0.f,0.f,0.f},{0.f,0.f,0.f,0.f}};
    uint_t qoff = (uint_t)(quad*16);
    uint_t aoffb = (uint_t)(lane*16);
#pragma unroll
    for (int k = 0; k < 9; ++k) {
        uint4 d = desc[(w*16 + n)*9 + k];
        uint_t vo00 = ((d.x & 0xffffu) << 7) + qoff;
        uint_t vo01 = ((d.x >> 16)     << 7) + qoff;
        uint_t vo10 = ((d.y & 0xffffu) << 7) + qoff;
        uint_t vo11 = ((d.y >> 16)     << 7) + qoff;
        float w00 = bflo(d.z), w01 = bfhi(d.z);
        float w10 = bflo(d.w), w11 = bfhi(d.w);
#pragma unroll
        for (int ks2 = 0; ks2 < 2; ++ks2) {
            int ks = k*2 + ks2;
            uint4 u00 = *(const uint4*)(xtc + vo00 + ks2*64);
            uint4 u01 = *(const uint4*)(xtc + vo01 + ks2*64);
            uint4 u10 = *(const uint4*)(xtc + vo10 + ks2*64);
            uint4 u11 = *(const uint4*)(xtc + vo11 + ks2*64);
            float2v q0 = (float2v){bflo(u00.x), bfhi(u00.x)} * w00;
            float2v q1 = (float2v){bflo(u00.y), bfhi(u00.y)} * w00;
            float2v q2 = (float2v){bflo(u00.z), bfhi(u00.z)} * w00;
            float2v q3 = (float2v){bflo(u00.w), bfhi(u00.w)} * w00;
            q0 += (float2v){bflo(u01.x), bfhi(u01.x)} * w01;
            q1 += (float2v){bflo(u01.y), bfhi(u01.y)} * w01;
            q2 += (float2v){bflo(u01.z), bfhi(u01.z)} * w01;
            q3 += (float2v){bflo(u01.w), bfhi(u01.w)} * w01;
            q0 += (float2v){bflo(u10.x), bfhi(u10.x)} * w10;
            q1 += (float2v){bflo(u10.y), bfhi(u10.y)} * w10;
            q2 += (float2v){bflo(u10.z), bfhi(u10.z)} * w10;
            q3 += (float2v){bflo(u10.w), bfhi(u10.w)} * w10;
            q0 += (float2v){bflo(u11.x), bfhi(u11.x)} * w11;
            q1 += (float2v){bflo(u11.y), bfhi(u11.y)} * w11;
            q2 += (float2v){bflo(u11.z), bfhi(u11.z)} * w11;
            q3 += (float2v){bflo(u11.w), bfhi(u11.w)} * w11;
            uint4 br = make_uint4(pkbf2(q0), pkbf2(q1), pkbf2(q2), pkbf2(q3));
            short8 bfr = __builtin_bit_cast(short8, br);
            uint_t ao = (uint_t)(ks*1024) + aoffb;
            short8 a0 = *(const short8*)(wtc + ao);
            short8 a1 = *(const short8*)(wtc + 18432 + ao);
            short8 a2 = *(const short8*)(wtc + 36864 + ao);
            short8 a3 = *(const short8*)(wtc + 55296 + ao);
            acc[0] = MFMA(a0, bfr, acc[0]);
            acc[1] = MFMA(a1, bfr, acc[1]);
            acc[2] = MFMA(a2, bfr, acc[2]);
            acc[3] = MFMA(a3, bfr, acc[3]);
        }
    }

    // ---- epilogue ----
#pragma unroll
    for (int mt = 0; mt < 4; ++mt) {
#pragma unroll
        for (int r = 0; r < 4; ++r) {
            int o = mt*16 + quad*4 + r;
            out[(((size_t)b*OUTq + o)*Hq + i)*Wq + j0 + n] = acc[mt][r];
        }
    }
}

// ---------------------------------------------------------------------------
extern "C" void kernel_launch(void* const* d_in, const int* in_sizes, int n_in,
                              void* d_out, int out_size, void* d_ws, size_t ws_size,
                              hipStream_t stream) {
    const float* x     = (const float*)d_in[0];
    const float* off_w = (const float*)d_in[1];
    const float* off_b = (const float*)d_in[2];
    const float* msk_w = (const float*)d_in[3];
    const float* msk_b = (const float*)d_in[4];
    const float* dcn_w = (const float*)d_in[5];
    float* out = (float*)d_out;

    char* ws = (char*)d_ws;
    ushort_t* xt   = (ushort_t*)ws;                  // 13,107,200 B
    ushort_t* wtf  = xt + (size_t)Bq*HWq*64;         //     73,728 B
    ushort_t* cwf2 = wtf + 4*KS*512;                 //     36,864 B

    hipLaunchKernelGGL(k_prep, dim3(HWq/64, Bq), dim3(256), 0, stream,
                       x, dcn_w, off_w, msk_w, xt, wtf, cwf2);
    hipLaunchKernelGGL(k_fused, dim3(1600), dim3(256), 0, stream,
                       xt, cwf2, off_b, msk_b, wtf, out);
}

// Round 10
// 133.580 us; speedup vs baseline: 1.2305x; 1.2305x over previous
//
#include <hip/hip_runtime.h>
#include <math.h>

#define Bq 4
#define Cq 64
#define Hq 160
#define Wq 160
#define HWq (Hq*Wq)      // 25600
#define OUTq 64
#define KKq 576          // Cq*9
#define KS  18           // KKq/32
#define SROW 584         // padded kk row (fp16 units); 1168 B, rows 16B-aligned
#define HSTRIDE 72       // halo px stride (ushorts) = 144 B

typedef __attribute__((ext_vector_type(8))) _Float16 half8;
typedef __attribute__((ext_vector_type(2))) _Float16 half2v;
typedef __attribute__((ext_vector_type(4))) float float4v;
typedef unsigned short ushort_t;
typedef unsigned int uint_t;

__device__ __forceinline__ ushort_t f2h(float f) {          // RNE f32->f16
    return __builtin_bit_cast(ushort_t, (_Float16)f);
}
__device__ __forceinline__ uint_t f2hdup(float f) {         // (h,h) packed
    uint_t u = (uint_t)f2h(f);
    return u | (u << 16);
}
__device__ __forceinline__ half2v h2(uint_t u) {
    return __builtin_bit_cast(half2v, u);
}
#define MFMA16(a,b,c) __builtin_amdgcn_mfma_f32_16x16x32_f16((a),(b),(c),0,0,0)

// ---------------------------------------------------------------------------
// K_prep: x NCHW f32 -> xt NHWC fp16; weight prepack on first 216 blocks.
//  wtf: A-frags of dcn_w (fp16), k-major kk = k*64+c, 4 m-tiles.
//  cwf2: per-tap conv A-frags (27 rows offset+mask, zero-padded to 32).
// ---------------------------------------------------------------------------
__global__ void __launch_bounds__(256) k_prep(const float* __restrict__ x,
                                              const float* __restrict__ dcn_w,
                                              const float* __restrict__ off_w,
                                              const float* __restrict__ msk_w,
                                              ushort_t* __restrict__ xt,
                                              ushort_t* __restrict__ wtf,
                                              ushort_t* __restrict__ cwf2) {
    __shared__ float tile[64][65];
    int b = blockIdx.y, hw0 = blockIdx.x * 64;
    int tid = threadIdx.x;
    int lane = tid & 63, grp = tid >> 6;
#pragma unroll
    for (int i = 0; i < 16; ++i) {
        int c = grp*16 + i;
        tile[c][lane] = x[(b*Cq + c)*HWq + hw0 + lane];
    }
    __syncthreads();
    int cp = tid & 31, hwg = tid >> 5;
#pragma unroll
    for (int it = 0; it < 8; ++it) {
        int hw = it*8 + hwg;
        uint_t v = (uint_t)f2h(tile[2*cp][hw]) | ((uint_t)f2h(tile[2*cp+1][hw]) << 16);
        *(uint_t*)(xt + ((size_t)b*HWq + hw0 + hw)*64 + 2*cp) = v;
    }
    if (blockIdx.y == 0 && blockIdx.x < 216) {
        int id = blockIdx.x*256 + tid;
        if (id < 4*KS*512) {
            int j = id & 7, ln = (id>>3) & 63, ks = (id>>9) % KS, g = id/(512*KS);
            int kk = ks*32 + (ln>>4)*8 + j;
            int c  = kk & 63, kt = kk >> 6;
            int m  = g*16 + (ln&15);
            wtf[id] = f2h(dcn_w[m*KKq + c*9 + kt]);
        }
        int id2 = id - 4*KS*512;
        if (id2 >= 0 && id2 < 9*2*2*512) {
            int j = id2 & 7, ln = (id2>>3) & 63;
            int ks2 = (id2>>9) & 1, g = (id2>>10) & 1, k = id2 >> 11;
            int co = g*16 + (ln&15);
            int c  = ks2*32 + (ln>>4)*8 + j;
            float w = 0.f;
            if (co < 18)      w = off_w[co*KKq + c*9 + k];
            else if (co < 27) w = msk_w[(co-18)*KKq + c*9 + k];
            cwf2[id2] = f2h(w);
        }
    }
}

// ---------------------------------------------------------------------------
// K_fused (r7 structure, fp16 datapath): per 16-px block:
//  halo stage -> offset/mask conv (K-split f16 MFMA) -> tap descriptors
//  (byte offsets + duplicated-fp16 premasked weights) -> Phase B sampling
//  (half-wave per (p,tap), 2 ch/lane, pure v_pk_fma_f16, no un/repack)
//  -> Phase C f16 MFMA matmul -> store.
// LDS: union{halo(7776)+partials(8192<-fits) | s_s(18688)} + s_A + s_W.
// ---------------------------------------------------------------------------
__global__ void __launch_bounds__(256, 7) k_fused(const ushort_t* __restrict__ xt,
                                                  const ushort_t* __restrict__ cwf2,
                                                  const float* __restrict__ off_b,
                                                  const float* __restrict__ msk_b,
                                                  const ushort_t* __restrict__ wtf,
                                                  float* __restrict__ out) {
    __shared__ __align__(16) char s_mem[16*SROW*2];          // 18,688 B
    __shared__ __align__(16) uint4 s_A[144];                 //  2,304 B
    __shared__ __align__(16) uint4 s_W[144];                 //  2,304 B
    ushort_t* halo   = (ushort_t*)s_mem;                     // [0, 7776)
    float*    s_part = (float*)(s_mem + 7776);               // [7776, 11872)
    ushort_t* s_s    = (ushort_t*)s_mem;                     // Phase B/C

    int blk = blockIdx.x;                 // 6400 = 4 * 160 * 10
    int jt = blk % 10, i = (blk/10) % Hq, b = blk/(10*Hq);
    int j0 = jt*16;
    int tid = threadIdx.x, lane = tid & 63, grp = tid >> 6;
    int n = lane & 15, quad = lane >> 4;

    // ---- Stage halo: 3 rows x 18 px x 64 ch fp16 ----
    const ushort_t* xtb = xt + (size_t)b*HWq*64;
    for (int t = tid; t < 432; t += 256) {
        int seg = t >> 3, sub = t & 7;
        int ky = seg / 18, px = seg % 18;
        int y = i + ky - 1, xx = j0 + px - 1;
        uint4 v = {0u,0u,0u,0u};
        if (y >= 0 && y < Hq && xx >= 0 && xx < Wq)
            v = *(const uint4*)(xtb + ((size_t)y*Wq + xx)*64 + sub*8);
        *(uint4*)(halo + (ky*18 + px)*HSTRIDE + sub*8) = v;
    }
    __syncthreads();

    // ---- Offset/mask conv: wave (gM, kh) over 9 K-steps each ----
    {
        int gM = grp & 1, kh = grp >> 1;
        float4v cacc = {0.f,0.f,0.f,0.f};
#pragma unroll
        for (int s = 0; s < 9; ++s) {
            int st = kh*9 + s;            // 0..17
            int k = st >> 1, ks2 = st & 1;
            int ky = k/3, kx = k - (k/3)*3;
            half8 a  = *(const half8*)(cwf2 + (size_t)(((k*2+gM)*2+ks2)*512 + lane*8));
            half8 bf = *(const half8*)(halo + (ky*18 + n + kx)*HSTRIDE + quad*8 + ks2*32);
            cacc = MFMA16(a, bf, cacc);
        }
        *(float4v*)(s_part + grp*256 + lane*4) = cacc;
    }
    __syncthreads();

    // ---- Phase A: tap descriptors from conv partials ----
    if (tid < 144) {
        int p = tid & 15, k = tid >> 4;
        #define RD(co) (s_part[(((co)>>4)*256)     + ((((co)&15)>>2)*16 + p)*4 + ((co)&3)] + \
                        s_part[(2 + ((co)>>4))*256 + ((((co)&15)>>2)*16 + p)*4 + ((co)&3)])
        float oy = RD(2*k)   + off_b[2*k];
        float ox = RD(2*k+1) + off_b[2*k+1];
        float mv = RD(18+k)  + msk_b[k];
        #undef RD
        float m = 1.f/(1.f + __expf(-mv));
        float py = oy + (float)(i - 1 + k/3);
        float px = ox + (float)(j0 + p - 1 + (k - (k/3)*3));
        float fy = floorf(py), fx = floorf(px);
        int y0 = (int)fy, x0 = (int)fx;
        float wy1 = py - fy, wx1 = px - fx;
        float wy0 = 1.f - wy1, wx0 = 1.f - wx1;
        bool vy0 = (y0 >= 0) & (y0 < Hq),   vy1 = (y0+1 >= 0) & (y0+1 < Hq);
        bool vx0 = (x0 >= 0) & (x0 < Wq),   vx1 = (x0+1 >= 0) & (x0+1 < Wq);
        int yc0 = min(max(y0,   0), Hq-1), yc1 = min(max(y0+1, 0), Hq-1);
        int xc0 = min(max(x0,   0), Wq-1), xc1 = min(max(x0+1, 0), Wq-1);
        s_A[tid] = make_uint4((uint_t)((yc0*Wq + xc0)*128),
                              (uint_t)((yc0*Wq + xc1)*128),
                              (uint_t)((yc1*Wq + xc0)*128),
                              (uint_t)((yc1*Wq + xc1)*128));
        s_W[tid] = make_uint4(f2hdup((vy0 && vx0) ? wy0*wx0*m : 0.f),
                              f2hdup((vy0 && vx1) ? wy0*wx1*m : 0.f),
                              f2hdup((vy1 && vx0) ? wy1*wx0*m : 0.f),
                              f2hdup((vy1 && vx1) ? wy1*wx1*m : 0.f));
    }
    __syncthreads();

    // ---- Phase B: half-wave per (p,tap), 2 ch/lane, pk_fma_f16 ----
    {
        int lane4 = (lane & 31) * 4;
        int halfi = lane >> 5;
        const char* xtbB = (const char*)xtb;
        char* s_sb = (char*)s_s;
#pragma unroll 2
        for (int iter = 0; iter < 18; ++iter) {
            int t2h = iter*8 + grp*2 + halfi;
            uint4 A  = s_A[t2h];
            uint4 Wt = s_W[t2h];
            uint_t dst = (uint_t)((t2h & 15)*(SROW*2) + (t2h >> 4)*128);
            uint_t u00 = *(const uint_t*)(xtbB + A.x + lane4);
            uint_t u01 = *(const uint_t*)(xtbB + A.y + lane4);
            uint_t u10 = *(const uint_t*)(xtbB + A.z + lane4);
            uint_t u11 = *(const uint_t*)(xtbB + A.w + lane4);
            half2v acc2 = h2(u00) * h2(Wt.x);
            acc2 = __builtin_elementwise_fma(h2(u01), h2(Wt.y), acc2);
            acc2 = __builtin_elementwise_fma(h2(u10), h2(Wt.z), acc2);
            acc2 = __builtin_elementwise_fma(h2(u11), h2(Wt.w), acc2);
            *(uint_t*)(s_sb + dst + lane4) = __builtin_bit_cast(uint_t, acc2);
        }
    }
    __syncthreads();

    // ---- Phase C: wave grp -> o rows [grp*16, +16), 16 pixels ----
    float4v acc = {0.f,0.f,0.f,0.f};
    const ushort_t* arow = wtf + ((size_t)(grp*KS)*64 + lane)*8;
    const ushort_t* brow = s_s + n*SROW + quad*8;
#pragma unroll
    for (int ks = 0; ks < KS; ++ks) {
        half8 a  = *(const half8*)(arow + ks*512);
        half8 bf = *(const half8*)(brow + ks*32);
        acc = MFMA16(a, bf, acc);
    }

#pragma unroll
    for (int r = 0; r < 4; ++r) {
        int o = grp*16 + quad*4 + r;
        out[(((size_t)b*OUTq + o)*Hq + i)*Wq + j0 + n] = acc[r];
    }
}

// ---------------------------------------------------------------------------
extern "C" void kernel_launch(void* const* d_in, const int* in_sizes, int n_in,
                              void* d_out, int out_size, void* d_ws, size_t ws_size,
                              hipStream_t stream) {
    const float* x     = (const float*)d_in[0];
    const float* off_w = (const float*)d_in[1];
    const float* off_b = (const float*)d_in[2];
    const float* msk_w = (const float*)d_in[3];
    const float* msk_b = (const float*)d_in[4];
    const float* dcn_w = (const float*)d_in[5];
    float* out = (float*)d_out;

    char* ws = (char*)d_ws;
    ushort_t* xt   = (ushort_t*)ws;                  // 13,107,200 B
    ushort_t* wtf  = xt + (size_t)Bq*HWq*64;         //     73,728 B
    ushort_t* cwf2 = wtf + 4*KS*512;                 //     36,864 B

    hipLaunchKernelGGL(k_prep, dim3(HWq/64, Bq), dim3(256), 0, stream,
                       x, dcn_w, off_w, msk_w, xt, wtf, cwf2);
    hipLaunchKernelGGL(k_fused, dim3(Bq*Hq*10), dim3(256), 0, stream,
                       xt, cwf2, off_b, msk_b, wtf, out);
}